// Round 24
// baseline (42.259 us; speedup 1.0000x reference)
//
#include <hip/hip_runtime.h>

typedef _Float16 half8 __attribute__((ext_vector_type(8)));
typedef __fp16 fp16x2 __attribute__((ext_vector_type(2)));
typedef float f32x16 __attribute__((ext_vector_type(16)));

#define CIN 3
#define COUT 32
// halo (f16): [3 ci][10 z][18 y][20 x]  (z=8 outputs + halo)
#define IXH 20
#define NYH 18
#define NZH 10
#define HY4  (IXH/2)          // 10 u32 per row
#define HZS4 (NYH*HY4)        // 180 u32 per z-plane
#define HCS4 (NZH*HZS4)       // 1800 u32 per ci
#define HN4  (3*HCS4)         // 5400 u32 total = 21600 B

#define LOG2E 1.4426950408889634f

// K order per ci (32 slots): pi: tt<8 -> t=tt ; 8..15 -> t=tt+8 ; 16..23 -> t=tt-8 ;
// 24..31 -> t=tt (24..26 real, 31@s5 = bias). t = kd*9+kh*3+kw.
// wpk layout: [s<6][hh<2][c<32][r<8] f16, pre-scaled by log2(e).
__global__ void prep_kernel(const float* __restrict__ w,
                            const float* __restrict__ b,
                            ushort* __restrict__ wpk)
{
    int i = threadIdx.x + blockIdx.x * 256;
    if (i >= 3072) return;
    int r  = i & 7;
    int c  = (i >> 3) & 31;
    int hh = (i >> 8) & 1;
    int s  = i >> 9;
    int ci = s >> 1;
    int tt = (s & 1) * 16 + hh * 8 + r;
    int t;
    if (tt < 8)       t = tt;
    else if (tt < 16) t = tt + 8;
    else if (tt < 24) t = tt - 8;
    else              t = tt;
    float val = 0.0f;
    if (t < 27) val = w[c * 81 + ci * 27 + t] * LOG2E;
    else if (s == 5 && tt == 31) val = b[c] * LOG2E;
    _Float16 hv = (_Float16)val;
    wpk[i] = *(ushort*)&hv;
}

__device__ __forceinline__ float quad_max(float v) {
    union { float f; int i; } a, b;
    a.f = v;
    b.i = __builtin_amdgcn_update_dpp(a.i, a.i, 0xB1, 0xF, 0xF, true);  // swap adjacent
    float m = fmaxf(v, b.f);
    a.f = m;
    b.i = __builtin_amdgcn_update_dpp(a.i, a.i, 0x4E, 0xF, 0xF, true);  // swap pairs
    return fmaxf(m, b.f);
}

// plain (256): 2nd arg is a register clamp ((256,6)/(256,8) -> spill storms
// R10/R14). z=8 per block (R23): FETCH -40%, prologue amortized, grid 1024.
// Staging g-loop is unroll 1 so only ONE f[11] batch is live (R23's #pragma
// unroll pipelined both batches -> +32 VGPR -> occupancy loss).
__global__ __launch_bounds__(256)
void conv_mfma_kernel(const float* __restrict__ x,
                      const ushort* __restrict__ wpk,
                      float* __restrict__ out)
{
    __shared__ ushort halo[2*HN4];

    const int tid = threadIdx.x;
    const int gx0 = blockIdx.x;          // n*8 + zqp
    const int n   = gx0 >> 3;
    const int zqp = gx0 & 7;             // z0 = zqp*8
    const int yb  = blockIdx.y;          // y0 = yb*16
    const int xh  = blockIdx.z;          // x0 = xh*16

    const int hh = (tid >> 5) & 1;
    const int cc = tid & 31;

    // ---- A fragments first (loads overlap staging) ----
    half8 af[6];
    #pragma unroll
    for (int s = 0; s < 6; ++s)
        af[s] = *(const half8*)(wpk + ((s*2 + hh)*32 + cc)*8);

    // ---- stage halo: 2 sequential batches of 11 (one f[11] live at a time) ----
    const int zg0 = zqp * 8 - 1;
    const int yg0 = yb * 16 - 1;
    const int xg0 = xh * 16 - 2;
    uint* h32w = (uint*)halo;
    #pragma unroll 1
    for (int g = 0; g < 2; ++g) {
        float2 f[11];
        #pragma unroll
        for (int i = 0; i < 11; ++i) {
            const int m = tid + (g*11 + i)*256;
            f[i] = make_float2(0.f, 0.f);
            if (m < HN4) {
                int pl  = m / 180;
                int rem = m - pl*180;
                int yy  = rem / 10;
                int xp  = rem - yy*10;
                int ci  = pl / 10;
                int zz  = pl - ci*10;
                int gz = zg0 + zz, gy = yg0 + yy, gxp = xg0 + 2*xp;
                if ((unsigned)gz < 64u && (unsigned)gy < 64u && (unsigned)gxp < 64u)
                    f[i] = *(const float2*)(x + (((size_t)(n*CIN+ci) << 6 | gz) << 12) + (gy << 6) + gxp);
            }
        }
        #pragma unroll
        for (int i = 0; i < 11; ++i) {
            const int m = tid + (g*11 + i)*256;
            if (m < HN4) {
                union { fp16x2 h; uint u; } cv;
                cv.h = __builtin_amdgcn_cvt_pkrtz(f[i].x, f[i].y);
                h32w[m] = cv.u;
            }
        }
    }
    __syncthreads();

    // ---- lane mapping: wave = y-quad; lane = (yo<2, xo<16) + hh K-half ----
    const int wv = tid >> 6;             // 0..3
    const int xo = cc & 15;
    const int yo = cc >> 4;
    const uint* h32 = (const uint*)halo;
    const uint sh = (xo + 1) & 1;        // 1 -> window starts at high half
    // v_perm sel: byte codes 0-3 pick src1(b=low u32), 4-7 pick src0(a=high u32)
    const uint SEL_W0 = sh ? 0x05040302u : 0x03020100u;  // [e0,e1] of a row pair
    const uint SEL_W1 = sh ? 0x07060504u : 0x05040302u;  // [e1,e2]
    const uint SEL_X  = sh ? 0x07060302u : 0x05040100u;  // [rowA e2, rowB e0]
    const uint shamt16 = sh * 16;
    const int  cb4   = ((xo + 1) >> 1) + (wv*4 + yo)*HY4 + hh*HZS4;

    #pragma unroll 1
    for (int zo = 0; zo < 2; ++zo) {
        float res[16];
        #pragma unroll
        for (int j = 0; j < 16; ++j) res[j] = 0.0f;

        #pragma unroll 2
        for (int tzl = 0; tzl < 4; ++tzl) {
            const int tz = zo*4 + tzl;
            #pragma unroll
            for (int ty = 0; ty < 2; ++ty) {
                // 3 raw per-lane row-pairs per (ci, p) for this ty
                const int sb4 = cb4 + tz*HZS4 + ty*(2*HY4);
                uint2 rw[3][2][3];
                #pragma unroll
                for (int ci = 0; ci < 3; ++ci)
                  #pragma unroll
                  for (int p = 0; p < 2; ++p) {
                    const uint* bp = h32 + sb4 + ci*HCS4 + p*HZS4;
                    #pragma unroll
                    for (int yy = 0; yy < 3; ++yy)
                        rw[ci][p][yy] = make_uint2(bp[yy*HY4], bp[yy*HY4 + 1]);
                  }

                f32x16 acc;
                #pragma unroll
                for (int j = 0; j < 16; ++j) acc[j] = 0.0f;

                #pragma unroll
                for (int ci = 0; ci < 3; ++ci) {
                    uint2 a0 = rw[ci][0][0], a1 = rw[ci][0][1], a2 = rw[ci][0][2];
                    uint2 b0 = rw[ci][1][0], b1 = rw[ci][1][1], b2 = rw[ci][1][2];
                    uint fe0, fe1, fe2, fe3, fo0, fo1, fo2, fo3;
                    if (hh == 0) {
                        fe0 = __builtin_amdgcn_perm(a0.y, a0.x, SEL_W0);
                        fe1 = __builtin_amdgcn_perm(a1.x, a0.y, SEL_X);
                        fe2 = __builtin_amdgcn_perm(a1.y, a1.x, SEL_W1);
                        fe3 = __builtin_amdgcn_perm(a2.y, a2.x, SEL_W0);
                        fo0 = __builtin_amdgcn_perm(b0.x, a2.y, SEL_X);
                        fo1 = __builtin_amdgcn_perm(b0.y, b0.x, SEL_W1);
                        fo2 = __builtin_amdgcn_perm(b1.y, b1.x, SEL_W0);
                        fo3 = __builtin_amdgcn_perm(b2.x, b1.y, SEL_X);
                    } else {
                        fe0 = __builtin_amdgcn_perm(a2.y, a2.x, SEL_W1);
                        fe1 = __builtin_amdgcn_perm(b0.y, b0.x, SEL_W0);
                        fe2 = __builtin_amdgcn_perm(b1.x, b0.y, SEL_X);
                        fe3 = __builtin_amdgcn_perm(b1.y, b1.x, SEL_W1);
                        fo0 = __builtin_amdgcn_perm(b2.y, b2.x, SEL_W0);
                        fo1 = (b2.y >> shamt16) & 0xffffu;
                        fo2 = 0u;
                        fo3 = (ci == 2) ? 0x3C000000u : 0u;   // bias partner 1.0
                    }
                    union { uint u[4]; half8 h; } ue, uo;
                    ue.u[0] = fe0; ue.u[1] = fe1; ue.u[2] = fe2; ue.u[3] = fe3;
                    uo.u[0] = fo0; uo.u[1] = fo1; uo.u[2] = fo2; uo.u[3] = fo3;
                    acc = __builtin_amdgcn_mfma_f32_32x32x16_f16(af[ci*2    ], ue.h, acc, 0, 0, 0);
                    acc = __builtin_amdgcn_mfma_f32_32x32x16_f16(af[ci*2 + 1], uo.h, acc, 0, 0, 0);
                }

                // softmax over 32 ch (no max-sub; weights pre-scaled by log2e)
                // scalar form — verified R15/R18. (inline-asm pk variant BROKEN: R12/R13)
                float e[16];
                #pragma unroll
                for (int j = 0; j < 16; ++j) e[j] = __builtin_amdgcn_exp2f(acc[j]);
                float s0 = (e[0]+e[1]) + (e[2]+e[3]);
                float s1 = (e[4]+e[5]) + (e[6]+e[7]);
                float s2 = (e[8]+e[9]) + (e[10]+e[11]);
                float s3 = (e[12]+e[13]) + (e[14]+e[15]);
                float sum = (s0+s1) + (s2+s3);
                sum += __shfl_xor(sum, 32);
                const float inv = __builtin_amdgcn_rcpf(sum);
                #pragma unroll
                for (int j = 0; j < 16; ++j) res[j] = fmaxf(res[j], e[j] * inv);
            }
        }

        // ---- x-pool over xo quads (DPP) + y-pool over yo pair ----
        #pragma unroll
        for (int j = 0; j < 16; ++j) {
            float v = quad_max(res[j]);
            res[j] = fmaxf(v, __shfl_xor(v, 16));
        }

        if (yo == 0 && (xo & 3) == 0) {
            const int xqg = xh*4 + (xo >> 2);
            const int yqg = yb*4 + wv;
            const int zg  = zqp*2 + zo;
            #pragma unroll
            for (int j = 0; j < 16; ++j) {
                int c = (j & 3) + 8*(j >> 2) + 4*hh;
                out[(((size_t)(n*COUT + c)*16 + zg)*16 + yqg)*16 + xqg] = res[j];
            }
        }
    }
}

extern "C" void kernel_launch(void* const* d_in, const int* in_sizes, int n_in,
                              void* d_out, int out_size, void* d_ws, size_t ws_size,
                              hipStream_t stream) {
    const float* x  = (const float*)d_in[0];
    const float* w  = (const float*)d_in[1];
    const float* b  = (const float*)d_in[2];
    float* out = (float*)d_out;
    ushort* wpk = (ushort*)d_ws;   // 3072 f16 = 6144 B scratch

    prep_kernel<<<12, 256, 0, stream>>>(w, b, wpk);

    dim3 grid(8 * 8, 4, 4);   // (n*zqp, yb, xh)
    conv_mfma_kernel<<<grid, 256, 0, stream>>>(x, wpk, out);
}

// Round 25
// 41.089 us; speedup vs baseline: 1.0285x; 1.0285x over previous
//
#include <hip/hip_runtime.h>

typedef _Float16 half8 __attribute__((ext_vector_type(8)));
typedef __fp16 fp16x2 __attribute__((ext_vector_type(2)));
typedef float f32x16 __attribute__((ext_vector_type(16)));

#define CIN 3
#define COUT 32
// halo (f16): [3 ci][6 z][18 y][20 x]
#define IXH 20
#define NYH 18
#define HY4  (IXH/2)          // 10 u32 per row
#define HZS4 (NYH*HY4)        // 180 u32 per z-plane
#define HCS4 (6*HZS4)         // 1080 u32 per ci
#define HN4  (3*HCS4)         // 3240 u32 total = 12960 B

#define LOG2E 1.4426950408889634f

// FINAL (R18 configuration — verified 41.1us, best of 24 rounds):
// - implicit-GEMM via mfma_f32_32x32x16_f16: A=weights (K pi-permuted, 81
//   taps ci-padded to 96, bias as tap k=95 vs B==1.0), B=im2col'd x from LDS
// - weights pre-scaled by log2(e) -> softmax exp is bare v_exp_f32, no max-sub
// - v_perm_b32 fragment build (no 64-bit shifts); cvt_pkrtz staging
// - per-lane z-column, softmax fully in-lane + one partner shfl
// - pool: in-lane z/y + DPP quad_max x + shfl(16) y
// - unroll 2 on tz (VGPR 68 = the occupancy/ILP sweet spot; unroll 4 -> 112
//   VGPR regressed, any launch-bounds 2nd arg -> spill storm)
__global__ void prep_kernel(const float* __restrict__ w,
                            const float* __restrict__ b,
                            ushort* __restrict__ wpk)
{
    int i = threadIdx.x + blockIdx.x * 256;
    if (i >= 3072) return;
    int r  = i & 7;
    int c  = (i >> 3) & 31;
    int hh = (i >> 8) & 1;
    int s  = i >> 9;
    int ci = s >> 1;
    int tt = (s & 1) * 16 + hh * 8 + r;
    int t;
    if (tt < 8)       t = tt;
    else if (tt < 16) t = tt + 8;
    else if (tt < 24) t = tt - 8;
    else              t = tt;
    float val = 0.0f;
    if (t < 27) val = w[c * 81 + ci * 27 + t] * LOG2E;
    else if (s == 5 && tt == 31) val = b[c] * LOG2E;
    _Float16 hv = (_Float16)val;
    wpk[i] = *(ushort*)&hv;
}

__device__ __forceinline__ float quad_max(float v) {
    union { float f; int i; } a, b;
    a.f = v;
    b.i = __builtin_amdgcn_update_dpp(a.i, a.i, 0xB1, 0xF, 0xF, true);  // swap adjacent
    float m = fmaxf(v, b.f);
    a.f = m;
    b.i = __builtin_amdgcn_update_dpp(a.i, a.i, 0x4E, 0xF, 0xF, true);  // swap pairs
    return fmaxf(m, b.f);
}

__global__ __launch_bounds__(256)
void conv_mfma_kernel(const float* __restrict__ x,
                      const ushort* __restrict__ wpk,
                      float* __restrict__ out)
{
    __shared__ ushort halo[2*HN4];

    const int tid = threadIdx.x;
    const int gx0 = blockIdx.x;          // n*16 + zq
    const int n   = gx0 >> 4;
    const int zq  = gx0 & 15;
    const int yb  = blockIdx.y;          // y0 = yb*16
    const int xh  = blockIdx.z;          // x0 = xh*16

    const int hh = (tid >> 5) & 1;
    const int cc = tid & 31;

    // ---- A fragments first (loads overlap staging) ----
    half8 af[6];
    #pragma unroll
    for (int s = 0; s < 6; ++s)
        af[s] = *(const half8*)(wpk + ((s*2 + hh)*32 + cc)*8);

    // ---- stage halo: issue ALL 13 loads, then cvt_pkrtz + write ----
    const int zg0 = zq * 4 - 1;
    const int yg0 = yb * 16 - 1;
    const int xg0 = xh * 16 - 2;
    uint* h32w = (uint*)halo;
    {
        float2 f[13];
        #pragma unroll
        for (int i = 0; i < 13; ++i) {
            const int m = tid + i*256;
            const bool mok = (i < 12) || (m < HN4);
            f[i] = make_float2(0.f, 0.f);
            if (mok) {
                int pl  = m / 180;
                int rem = m - pl*180;
                int yy  = rem / 10;
                int xp  = rem - yy*10;
                int ci  = pl / 6;
                int zz  = pl - ci*6;
                int gz = zg0 + zz, gy = yg0 + yy, gxp = xg0 + 2*xp;
                if ((unsigned)gz < 64u && (unsigned)gy < 64u && (unsigned)gxp < 64u)
                    f[i] = *(const float2*)(x + (((size_t)(n*CIN+ci) << 6 | gz) << 12) + (gy << 6) + gxp);
            }
        }
        #pragma unroll
        for (int i = 0; i < 13; ++i) {
            const int m = tid + i*256;
            if ((i < 12) || (m < HN4)) {
                union { fp16x2 h; uint u; } cv;
                cv.h = __builtin_amdgcn_cvt_pkrtz(f[i].x, f[i].y);
                h32w[m] = cv.u;
            }
        }
    }
    __syncthreads();

    // ---- lane mapping: wave = y-quad; lane = (yo<2, xo<16) + hh K-half ----
    const int wv = tid >> 6;             // 0..3
    const int xo = cc & 15;
    const int yo = cc >> 4;
    const uint* h32 = (const uint*)halo;
    const uint sh = (xo + 1) & 1;        // 1 -> window starts at high half
    // v_perm sel: byte codes 0-3 pick src1(b=low u32), 4-7 pick src0(a=high u32)
    const uint SEL_W0 = sh ? 0x05040302u : 0x03020100u;  // [e0,e1] of a row pair
    const uint SEL_W1 = sh ? 0x07060504u : 0x05040302u;  // [e1,e2]
    const uint SEL_X  = sh ? 0x07060302u : 0x05040100u;  // [rowA e2, rowB e0]
    const uint shamt16 = sh * 16;
    const int  cb4   = ((xo + 1) >> 1) + (wv*4 + yo)*HY4 + hh*HZS4;

    f32x16 res;
    #pragma unroll
    for (int j = 0; j < 16; ++j) res[j] = 0.0f;

    #pragma unroll 2
    for (int tz = 0; tz < 4; ++tz) {
        #pragma unroll
        for (int ty = 0; ty < 2; ++ty) {
            // 3 raw per-lane row-pairs per (ci, p) for this ty (y = wv*4 + yo + ty*2)
            const int sb4 = cb4 + tz*HZS4 + ty*(2*HY4);
            uint2 rw[3][2][3];
            #pragma unroll
            for (int ci = 0; ci < 3; ++ci)
              #pragma unroll
              for (int p = 0; p < 2; ++p) {
                const uint* bp = h32 + sb4 + ci*HCS4 + p*HZS4;
                #pragma unroll
                for (int yy = 0; yy < 3; ++yy)
                    rw[ci][p][yy] = make_uint2(bp[yy*HY4], bp[yy*HY4 + 1]);
              }

            f32x16 acc;
            #pragma unroll
            for (int j = 0; j < 16; ++j) acc[j] = 0.0f;

            #pragma unroll
            for (int ci = 0; ci < 3; ++ci) {
                uint2 a0 = rw[ci][0][0], a1 = rw[ci][0][1], a2 = rw[ci][0][2];
                uint2 b0 = rw[ci][1][0], b1 = rw[ci][1][1], b2 = rw[ci][1][2];
                uint fe0, fe1, fe2, fe3, fo0, fo1, fo2, fo3;
                if (hh == 0) {
                    fe0 = __builtin_amdgcn_perm(a0.y, a0.x, SEL_W0);
                    fe1 = __builtin_amdgcn_perm(a1.x, a0.y, SEL_X);
                    fe2 = __builtin_amdgcn_perm(a1.y, a1.x, SEL_W1);
                    fe3 = __builtin_amdgcn_perm(a2.y, a2.x, SEL_W0);
                    fo0 = __builtin_amdgcn_perm(b0.x, a2.y, SEL_X);
                    fo1 = __builtin_amdgcn_perm(b0.y, b0.x, SEL_W1);
                    fo2 = __builtin_amdgcn_perm(b1.y, b1.x, SEL_W0);
                    fo3 = __builtin_amdgcn_perm(b2.x, b1.y, SEL_X);
                } else {
                    fe0 = __builtin_amdgcn_perm(a2.y, a2.x, SEL_W1);
                    fe1 = __builtin_amdgcn_perm(b0.y, b0.x, SEL_W0);
                    fe2 = __builtin_amdgcn_perm(b1.x, b0.y, SEL_X);
                    fe3 = __builtin_amdgcn_perm(b1.y, b1.x, SEL_W1);
                    fo0 = __builtin_amdgcn_perm(b2.y, b2.x, SEL_W0);
                    fo1 = (b2.y >> shamt16) & 0xffffu;
                    fo2 = 0u;
                    fo3 = (ci == 2) ? 0x3C000000u : 0u;   // bias partner 1.0
                }
                union { uint u[4]; half8 h; } ue, uo;
                ue.u[0] = fe0; ue.u[1] = fe1; ue.u[2] = fe2; ue.u[3] = fe3;
                uo.u[0] = fo0; uo.u[1] = fo1; uo.u[2] = fo2; uo.u[3] = fo3;
                acc = __builtin_amdgcn_mfma_f32_32x32x16_f16(af[ci*2    ], ue.h, acc, 0, 0, 0);
                acc = __builtin_amdgcn_mfma_f32_32x32x16_f16(af[ci*2 + 1], uo.h, acc, 0, 0, 0);
            }

            // softmax over 32 ch (no max-sub; weights pre-scaled by log2e)
            // scalar form — verified R15/R18. (inline-asm pk variant BROKEN: R12/R13)
            float e[16];
            #pragma unroll
            for (int j = 0; j < 16; ++j) e[j] = __builtin_amdgcn_exp2f(acc[j]);
            float s0 = (e[0]+e[1]) + (e[2]+e[3]);
            float s1 = (e[4]+e[5]) + (e[6]+e[7]);
            float s2 = (e[8]+e[9]) + (e[10]+e[11]);
            float s3 = (e[12]+e[13]) + (e[14]+e[15]);
            float sum = (s0+s1) + (s2+s3);
            sum += __shfl_xor(sum, 32);
            const float inv = __builtin_amdgcn_rcpf(sum);
            #pragma unroll
            for (int j = 0; j < 16; ++j) res[j] = fmaxf(res[j], e[j] * inv);
        }
    }

    // ---- x-pool over xo quads (DPP) + y-pool over yo pair ----
    #pragma unroll
    for (int j = 0; j < 16; ++j) {
        float v = quad_max(res[j]);
        res[j] = fmaxf(v, __shfl_xor(v, 16));
    }

    if (yo == 0 && (xo & 3) == 0) {
        const int xqg = xh*4 + (xo >> 2);
        const int yqg = yb*4 + wv;
        #pragma unroll
        for (int j = 0; j < 16; ++j) {
            int c = (j & 3) + 8*(j >> 2) + 4*hh;
            out[(((size_t)(n*COUT + c)*16 + zq)*16 + yqg)*16 + xqg] = res[j];
        }
    }
}

extern "C" void kernel_launch(void* const* d_in, const int* in_sizes, int n_in,
                              void* d_out, int out_size, void* d_ws, size_t ws_size,
                              hipStream_t stream) {
    const float* x  = (const float*)d_in[0];
    const float* w  = (const float*)d_in[1];
    const float* b  = (const float*)d_in[2];
    float* out = (float*)d_out;
    ushort* wpk = (ushort*)d_ws;   // 3072 f16 = 6144 B scratch

    prep_kernel<<<12, 256, 0, stream>>>(w, b, wpk);

    dim3 grid(8 * 16, 4, 4);   // (n*zq, yb, xh)
    conv_mfma_kernel<<<grid, 256, 0, stream>>>(x, wpk, out);
}